// Round 2
// baseline (136.898 us; speedup 1.0000x reference)
//
#include <hip/hip_runtime.h>

#define NROW 8192
#define MDIM 128
#define KLAB 16
#define NSLAB 64                     // 8192 / 128 supertile rows
#define NTILE (NSLAB*(NSLAB+1)/2)    // 2080 upper-tri supertiles
#define MARGINP 16.970562748477139f  // 1.5 * sqrt(128): margin pre-scaled so we defer /sqrt(128)

typedef __attribute__((ext_vector_type(8))) short  s16x8;
typedef __attribute__((ext_vector_type(4))) float  f32x4;

__device__ __forceinline__ unsigned short f2bf(float x) {
  unsigned u = __float_as_uint(x);            // RTNE bf16, inputs are finite
  return (unsigned short)((u + 0x7FFFu + ((u >> 16) & 1u)) >> 16);
}

// One wave per row: bf16 convert + sum-of-squares + label bitmask + popcount.
__global__ void prep_kernel(const float* __restrict__ feat, const int* __restrict__ label,
                            unsigned short* __restrict__ fbf, float* __restrict__ sq,
                            int* __restrict__ maskA, int* __restrict__ nposA) {
  int wave = threadIdx.x >> 6, lane = threadIdx.x & 63;
  int row = blockIdx.x * 4 + wave;
  float2 v = *reinterpret_cast<const float2*>(feat + (size_t)row * MDIM + lane * 2);
  ushort2 st; st.x = f2bf(v.x); st.y = f2bf(v.y);
  *reinterpret_cast<ushort2*>(fbf + (size_t)row * MDIM + lane * 2) = st;
  float s = v.x * v.x + v.y * v.y;
  #pragma unroll
  for (int off = 32; off >= 1; off >>= 1) s += __shfl_xor(s, off);
  int lab = (lane < KLAB) ? label[row * KLAB + lane] : 0;
  unsigned long long bal = __ballot(lab > 0);
  if (lane == 0) {
    unsigned m = (unsigned)(bal & 0xFFFFu);
    sq[row]    = s;
    maskA[row] = (int)m;
    nposA[row] = __popc(m);
  }
}

// Block = 4 waves = one 128x128 supertile (bi<=bj upper triangle).
// Wave w owns i-rows [bi*128+w*32, +32); sweeps 4 j-subtiles of 32 cols of bj's slab.
// mfma_f32_16x16x32_bf16: A lane l holds A[l&15][(l>>4)*8+j]; C/D col=lane&15, row=(lane>>4)*4+reg.
__global__ __launch_bounds__(256) void pair_main(
    const unsigned short* __restrict__ fbf, const float* __restrict__ sq,
    const int* __restrict__ maskA, const int* __restrict__ nposA,
    float* __restrict__ accum) {
  // exact weight LUT: w[inter][npos_i+npos_j]; union = ns - inter.
  __shared__ float wtab[17 * 33];
  for (int t = threadIdx.x; t < 17 * 33; t += 256) {
    int inter = t / 33, ns = t % 33, uni = ns - inter;
    float w;
    if (inter == 0)      w = (ns == 0) ? __int_as_float(0x7FC00000) : -1.0f; // 0/0->NaN, w==0 -> -1
    else if (uni <= 0)   w = 0.0f;                                            // unreachable combos
    else                 w = (float)inter / (float)uni;                       // exact IEEE div
    wtab[t] = w;
  }
  __syncthreads();

  // decode linear block id -> (bi, bj) with bi <= bj
  int bi = 0, rem = blockIdx.x;
  while (rem >= NSLAB - bi) { rem -= NSLAB - bi; bi++; }
  int bj = bi + rem;

  int wv = threadIdx.x >> 6, lane = threadIdx.x & 63;
  int l15 = lane & 15, lg = lane >> 4;   // lg: k-group for A/B, row-group for C/D
  int i0 = bi * 128 + wv * 32;
  int j0 = bj * 128;
  const char* fb = (const char*)fbf;

  // A fragments for this wave's 32 rows, whole K=128 in registers (32 VGPR)
  s16x8 af[2][4];
  #pragma unroll
  for (int fi = 0; fi < 2; fi++)
    #pragma unroll
    for (int ks = 0; ks < 4; ks++)
      af[fi][ks] = *reinterpret_cast<const s16x8*>(
          fb + (size_t)(i0 + fi * 16 + l15) * 256 + ks * 64 + lg * 16);

  // i-row metadata at C/D row positions: row = fi*16 + lg*4 + r
  float sqi[2][4]; int mi[2][4], ni[2][4];
  #pragma unroll
  for (int fi = 0; fi < 2; fi++)
    #pragma unroll
    for (int r = 0; r < 4; r++) {
      int ir = i0 + fi * 16 + lg * 4 + r;
      sqi[fi][r] = sq[ir]; mi[fi][r] = maskA[ir]; ni[fi][r] = nposA[ir];
    }

  bool diag = (bi == bj);
  float sum = 0.0f;

  for (int js = 0; js < 4; js++) {
    int j0s = j0 + js * 32;
    s16x8 bfr[2][4];
    #pragma unroll
    for (int fj = 0; fj < 2; fj++)
      #pragma unroll
      for (int ks = 0; ks < 4; ks++)
        bfr[fj][ks] = *reinterpret_cast<const s16x8*>(
            fb + (size_t)(j0s + fj * 16 + l15) * 256 + ks * 64 + lg * 16);

    float sqj[2]; int mj[2], nj[2];
    #pragma unroll
    for (int fj = 0; fj < 2; fj++) {
      int jr = j0s + fj * 16 + l15;
      sqj[fj] = sq[jr]; mj[fj] = maskA[jr]; nj[fj] = nposA[jr];
    }

    f32x4 acc[2][2];
    #pragma unroll
    for (int fi = 0; fi < 2; fi++)
      #pragma unroll
      for (int fj = 0; fj < 2; fj++)
        acc[fi][fj] = (f32x4){0.f, 0.f, 0.f, 0.f};

    #pragma unroll
    for (int ks = 0; ks < 4; ks++)
      #pragma unroll
      for (int fi = 0; fi < 2; fi++)
        #pragma unroll
        for (int fj = 0; fj < 2; fj++)
          acc[fi][fj] = __builtin_amdgcn_mfma_f32_16x16x32_bf16(
              af[fi][ks], bfr[fj][ks], acc[fi][fj], 0, 0, 0);

    if (!diag) {
      #pragma unroll
      for (int fi = 0; fi < 2; fi++)
        #pragma unroll
        for (int fj = 0; fj < 2; fj++)
          #pragma unroll
          for (int r = 0; r < 4; r++) {
            float g  = acc[fi][fj][r];
            float d2 = fmaf(-2.0f, g, sqi[fi][r] + sqj[fj]);
            float t  = fminf(sqrtf(fmaxf(d2, 0.0f)), MARGINP);
            int inter = __popc(mi[fi][r] & mj[fj]);
            float w  = wtab[inter * 33 + ni[fi][r] + nj[fj]];
            sum = fmaf(w, t, sum);
          }
    } else {
      #pragma unroll
      for (int fi = 0; fi < 2; fi++)
        #pragma unroll
        for (int fj = 0; fj < 2; fj++)
          #pragma unroll
          for (int r = 0; r < 4; r++) {
            float g  = acc[fi][fj][r];
            float d2 = fmaf(-2.0f, g, sqi[fi][r] + sqj[fj]);
            float t  = fminf(sqrtf(fmaxf(d2, 0.0f)), MARGINP);
            int inter = __popc(mi[fi][r] & mj[fj]);
            float w  = wtab[inter * 33 + ni[fi][r] + nj[fj]];
            int il = wv * 32 + fi * 16 + lg * 4 + r;
            int jl = js * 32 + fj * 16 + l15;
            float f = (jl > il) ? 2.0f : ((jl == il) ? 1.0f : 0.0f);
            sum = fmaf(f * w, t, sum);
          }
    }
  }

  #pragma unroll
  for (int off = 32; off >= 1; off >>= 1) sum += __shfl_xor(sum, off);
  if (lane == 0) atomicAdd(accum, diag ? sum : 2.0f * sum);
}

__global__ void finalize_kernel(const float* __restrict__ accum, float* __restrict__ out) {
  if (threadIdx.x == 0) {
    // undo deferred scales: /sqrt(128) and /n^2
    out[0] = (float)((double)accum[0] * (1.0 / (11.313708498984760 * 67108864.0)));
  }
}

extern "C" void kernel_launch(void* const* d_in, const int* in_sizes, int n_in,
                              void* d_out, int out_size, void* d_ws, size_t ws_size,
                              hipStream_t stream) {
  const float* feat  = (const float*)d_in[0];
  const int*   label = (const int*)d_in[1];
  char* ws = (char*)d_ws;
  float* accum          = (float*)ws;                    // 4 B (pad to 256)
  float* sq             = (float*)(ws + 256);            // 32 KB
  int*   maskA          = (int*)(ws + 256 + 32768);      // 32 KB
  int*   nposA          = (int*)(ws + 256 + 65536);      // 32 KB
  unsigned short* fbf   = (unsigned short*)(ws + 256 + 98304); // 2 MB bf16 feature
  float* out = (float*)d_out;

  (void)hipMemsetAsync(accum, 0, sizeof(float), stream);
  prep_kernel<<<NROW / 4, 256, 0, stream>>>(feat, label, fbf, sq, maskA, nposA);
  pair_main<<<NTILE, 256, 0, stream>>>(fbf, sq, maskA, nposA, accum);
  finalize_kernel<<<1, 64, 0, stream>>>(accum, out);
}

// Round 3
// 62.144 us; speedup vs baseline: 2.2029x; 2.2029x over previous
//
#include <hip/hip_runtime.h>

#define NROW 8192
#define MDIM 128
#define KLAB 16
#define NSLAB 64                     // 8192 / 128 supertile rows
#define NTILE (NSLAB*(NSLAB+1)/2)    // 2080 upper-tri supertiles
#define MARGINP 16.970562748477139f  // 1.5 * sqrt(128): margin pre-scaled so we defer /sqrt(128)

typedef __attribute__((ext_vector_type(8))) short  s16x8;
typedef __attribute__((ext_vector_type(4))) float  f32x4;

__device__ __forceinline__ unsigned short f2bf(float x) {
  unsigned u = __float_as_uint(x);            // RTNE bf16, inputs are finite
  return (unsigned short)((u + 0x7FFFu + ((u >> 16) & 1u)) >> 16);
}

// One wave per row: bf16 convert + sum-of-squares + label bitmask + popcount.
__global__ void prep_kernel(const float* __restrict__ feat, const int* __restrict__ label,
                            unsigned short* __restrict__ fbf, float* __restrict__ sq,
                            int* __restrict__ maskA, int* __restrict__ nposA) {
  int wave = threadIdx.x >> 6, lane = threadIdx.x & 63;
  int row = blockIdx.x * 4 + wave;
  float2 v = *reinterpret_cast<const float2*>(feat + (size_t)row * MDIM + lane * 2);
  ushort2 st; st.x = f2bf(v.x); st.y = f2bf(v.y);
  *reinterpret_cast<ushort2*>(fbf + (size_t)row * MDIM + lane * 2) = st;
  float s = v.x * v.x + v.y * v.y;
  #pragma unroll
  for (int off = 32; off >= 1; off >>= 1) s += __shfl_xor(s, off);
  int lab = (lane < KLAB) ? label[row * KLAB + lane] : 0;
  unsigned long long bal = __ballot(lab > 0);
  if (lane == 0) {
    unsigned m = (unsigned)(bal & 0xFFFFu);
    sq[row]    = s;
    maskA[row] = (int)m;
    nposA[row] = __popc(m);
  }
}

// Block = 4 waves = one 128x128 supertile (bi<=bj upper triangle).
// Wave w owns i-rows [bi*128+w*32, +32); sweeps 4 j-subtiles of 32 cols of bj's slab.
// mfma_f32_16x16x32_bf16: A lane l holds A[l&15][(l>>4)*8+j]; C/D col=lane&15, row=(lane>>4)*4+reg.
__global__ __launch_bounds__(256) void pair_main(
    const unsigned short* __restrict__ fbf, const float* __restrict__ sq,
    const int* __restrict__ maskA, const int* __restrict__ nposA,
    float* __restrict__ part) {
  // exact weight LUT: w[inter][npos_i+npos_j]; union = ns - inter.
  __shared__ float wtab[17 * 33];
  __shared__ float bsum[4];
  for (int t = threadIdx.x; t < 17 * 33; t += 256) {
    int inter = t / 33, ns = t % 33, uni = ns - inter;
    float w;
    if (inter == 0)      w = (ns == 0) ? __int_as_float(0x7FC00000) : -1.0f; // 0/0->NaN, w==0 -> -1
    else if (uni <= 0)   w = 0.0f;                                            // unreachable combos
    else                 w = (float)inter / (float)uni;                       // exact IEEE div
    wtab[t] = w;
  }
  __syncthreads();

  // decode linear block id -> (bi, bj) with bi <= bj
  int bi = 0, rem = blockIdx.x;
  while (rem >= NSLAB - bi) { rem -= NSLAB - bi; bi++; }
  int bj = bi + rem;

  int wv = threadIdx.x >> 6, lane = threadIdx.x & 63;
  int l15 = lane & 15, lg = lane >> 4;   // lg: k-group for A/B, row-group for C/D
  int i0 = bi * 128 + wv * 32;
  int j0 = bj * 128;
  const char* fb = (const char*)fbf;

  // A fragments for this wave's 32 rows, whole K=128 in registers (32 VGPR)
  s16x8 af[2][4];
  #pragma unroll
  for (int fi = 0; fi < 2; fi++)
    #pragma unroll
    for (int ks = 0; ks < 4; ks++)
      af[fi][ks] = *reinterpret_cast<const s16x8*>(
          fb + (size_t)(i0 + fi * 16 + l15) * 256 + ks * 64 + lg * 16);

  // i-row metadata at C/D row positions: row = fi*16 + lg*4 + r
  float sqi[2][4]; int mi[2][4], ni[2][4];
  #pragma unroll
  for (int fi = 0; fi < 2; fi++)
    #pragma unroll
    for (int r = 0; r < 4; r++) {
      int ir = i0 + fi * 16 + lg * 4 + r;
      sqi[fi][r] = sq[ir]; mi[fi][r] = maskA[ir]; ni[fi][r] = nposA[ir];
    }

  bool diag = (bi == bj);
  float sum = 0.0f;

  for (int js = 0; js < 4; js++) {
    int j0s = j0 + js * 32;
    s16x8 bfr[2][4];
    #pragma unroll
    for (int fj = 0; fj < 2; fj++)
      #pragma unroll
      for (int ks = 0; ks < 4; ks++)
        bfr[fj][ks] = *reinterpret_cast<const s16x8*>(
            fb + (size_t)(j0s + fj * 16 + l15) * 256 + ks * 64 + lg * 16);

    float sqj[2]; int mj[2], nj[2];
    #pragma unroll
    for (int fj = 0; fj < 2; fj++) {
      int jr = j0s + fj * 16 + l15;
      sqj[fj] = sq[jr]; mj[fj] = maskA[jr]; nj[fj] = nposA[jr];
    }

    f32x4 acc[2][2];
    #pragma unroll
    for (int fi = 0; fi < 2; fi++)
      #pragma unroll
      for (int fj = 0; fj < 2; fj++)
        acc[fi][fj] = (f32x4){0.f, 0.f, 0.f, 0.f};

    #pragma unroll
    for (int ks = 0; ks < 4; ks++)
      #pragma unroll
      for (int fi = 0; fi < 2; fi++)
        #pragma unroll
        for (int fj = 0; fj < 2; fj++)
          acc[fi][fj] = __builtin_amdgcn_mfma_f32_16x16x32_bf16(
              af[fi][ks], bfr[fj][ks], acc[fi][fj], 0, 0, 0);

    if (!diag) {
      #pragma unroll
      for (int fi = 0; fi < 2; fi++)
        #pragma unroll
        for (int fj = 0; fj < 2; fj++)
          #pragma unroll
          for (int r = 0; r < 4; r++) {
            float g  = acc[fi][fj][r];
            float d2 = fmaf(-2.0f, g, sqi[fi][r] + sqj[fj]);
            float t  = fminf(sqrtf(fmaxf(d2, 0.0f)), MARGINP);
            int inter = __popc(mi[fi][r] & mj[fj]);
            float w  = wtab[inter * 33 + ni[fi][r] + nj[fj]];
            sum = fmaf(w, t, sum);
          }
    } else {
      #pragma unroll
      for (int fi = 0; fi < 2; fi++)
        #pragma unroll
        for (int fj = 0; fj < 2; fj++)
          #pragma unroll
          for (int r = 0; r < 4; r++) {
            float g  = acc[fi][fj][r];
            float d2 = fmaf(-2.0f, g, sqi[fi][r] + sqj[fj]);
            float t  = fminf(sqrtf(fmaxf(d2, 0.0f)), MARGINP);
            int inter = __popc(mi[fi][r] & mj[fj]);
            float w  = wtab[inter * 33 + ni[fi][r] + nj[fj]];
            int il = wv * 32 + fi * 16 + lg * 4 + r;
            int jl = js * 32 + fj * 16 + l15;
            float f = (jl > il) ? 2.0f : ((jl == il) ? 1.0f : 0.0f);
            sum = fmaf(f * w, t, sum);
          }
    }
  }

  #pragma unroll
  for (int off = 32; off >= 1; off >>= 1) sum += __shfl_xor(sum, off);
  if (lane == 0) bsum[wv] = sum;
  __syncthreads();
  if (threadIdx.x == 0) {
    float s = bsum[0] + bsum[1] + bsum[2] + bsum[3];
    part[blockIdx.x] = diag ? s : 2.0f * s;   // one plain store per block, no atomics
  }
}

// Single block: sum 2080 partials (double accum) + apply deferred scales.
__global__ void reduce_kernel(const float* __restrict__ part, float* __restrict__ out) {
  int tid = threadIdx.x;
  double s = 0.0;
  for (int i = tid; i < NTILE; i += 256) s += (double)part[i];
  #pragma unroll
  for (int off = 32; off >= 1; off >>= 1) s += __shfl_xor(s, off);
  __shared__ double wsum[4];
  int wv = tid >> 6, lane = tid & 63;
  if (lane == 0) wsum[wv] = s;
  __syncthreads();
  if (tid == 0) {
    double t = wsum[0] + wsum[1] + wsum[2] + wsum[3];
    // undo deferred scales: /sqrt(128) and /n^2
    out[0] = (float)(t * (1.0 / (11.313708498984760 * 67108864.0)));
  }
}

extern "C" void kernel_launch(void* const* d_in, const int* in_sizes, int n_in,
                              void* d_out, int out_size, void* d_ws, size_t ws_size,
                              hipStream_t stream) {
  const float* feat  = (const float*)d_in[0];
  const int*   label = (const int*)d_in[1];
  char* ws = (char*)d_ws;
  float* part           = (float*)ws;                         // 2080 floats (8448 B reserved)
  float* sq             = (float*)(ws + 8448);                // 32 KB
  int*   maskA          = (int*)(ws + 8448 + 32768);          // 32 KB
  int*   nposA          = (int*)(ws + 8448 + 65536);          // 32 KB
  unsigned short* fbf   = (unsigned short*)(ws + 8448 + 98304); // 2 MB bf16 feature
  float* out = (float*)d_out;

  prep_kernel<<<NROW / 4, 256, 0, stream>>>(feat, label, fbf, sq, maskA, nposA);
  pair_main<<<NTILE, 256, 0, stream>>>(fbf, sq, maskA, nposA, part);
  reduce_kernel<<<1, 256, 0, stream>>>(part, out);
}

// Round 4
// 61.897 us; speedup vs baseline: 2.2117x; 1.0040x over previous
//
#include <hip/hip_runtime.h>

#define NROW 8192
#define MDIM 128
#define KLAB 16
#define NSLAB 64                     // 8192 / 128 supertile rows
#define NTILE (NSLAB*(NSLAB+1)/2)    // 2080 upper-tri supertiles
#define MARGINP 16.970562748477139f  // 1.5 * sqrt(128): margin pre-scaled so we defer /sqrt(128)

typedef __attribute__((ext_vector_type(8))) short  s16x8;
typedef __attribute__((ext_vector_type(4))) float  f32x4;

#if __has_builtin(__builtin_amdgcn_sqrtf)
#define FSQRT(x) __builtin_amdgcn_sqrtf(x)
#else
#define FSQRT(x) sqrtf(x)
#endif
#if __has_builtin(__builtin_amdgcn_rcpf)
#define FRCP(x) __builtin_amdgcn_rcpf(x)
#else
#define FRCP(x) (1.0f / (x))
#endif

__device__ __forceinline__ unsigned short f2bf(float x) {
  unsigned u = __float_as_uint(x);            // RTNE bf16, inputs are finite
  return (unsigned short)((u + 0x7FFFu + ((u >> 16) & 1u)) >> 16);
}

// One wave per row: bf16 convert + sum-of-squares + label bitmask.
__global__ void prep_kernel(const float* __restrict__ feat, const int* __restrict__ label,
                            unsigned short* __restrict__ fbf, float* __restrict__ sq,
                            int* __restrict__ maskA) {
  int wave = threadIdx.x >> 6, lane = threadIdx.x & 63;
  int row = blockIdx.x * 4 + wave;
  float2 v = *reinterpret_cast<const float2*>(feat + (size_t)row * MDIM + lane * 2);
  ushort2 st; st.x = f2bf(v.x); st.y = f2bf(v.y);
  *reinterpret_cast<ushort2*>(fbf + (size_t)row * MDIM + lane * 2) = st;
  float s = v.x * v.x + v.y * v.y;
  #pragma unroll
  for (int off = 32; off >= 1; off >>= 1) s += __shfl_xor(s, off);
  int lab = (lane < KLAB) ? label[row * KLAB + lane] : 0;
  unsigned long long bal = __ballot(lab > 0);
  if (lane == 0) {
    sq[row]    = s;
    maskA[row] = (int)(unsigned)(bal & 0xFFFFu);
  }
}

// Block = 4 waves = one 128x128 supertile (bi<=bj upper triangle).
// Wave w owns i-rows [bi*128+w*32, +32); sweeps 4 j-subtiles of 32 cols, 1-ahead pipelined.
// mfma_f32_16x16x32_bf16 layout as verified in round 2 (absmax == 0).
__global__ __launch_bounds__(256) void pair_main(
    const unsigned short* __restrict__ fbf, const float* __restrict__ sq,
    const int* __restrict__ maskA, float* __restrict__ part) {
  __shared__ float bsum[4];

  // decode linear block id -> (bi, bj) with bi <= bj
  int bi = 0, rem = blockIdx.x;
  while (rem >= NSLAB - bi) { rem -= NSLAB - bi; bi++; }
  int bj = bi + rem;

  int wv = threadIdx.x >> 6, lane = threadIdx.x & 63;
  int l15 = lane & 15, lg = lane >> 4;   // lg: k-group for A/B, row-group for C/D
  int i0 = bi * 128 + wv * 32;
  int j0 = bj * 128;
  const char* fb = (const char*)fbf;

  // A fragments: this wave's 32 rows, whole K=128 (32 VGPR)
  s16x8 af[2][4];
  #pragma unroll
  for (int fi = 0; fi < 2; fi++)
    #pragma unroll
    for (int ks = 0; ks < 4; ks++)
      af[fi][ks] = *reinterpret_cast<const s16x8*>(
          fb + (size_t)(i0 + fi * 16 + l15) * 256 + ks * 64 + lg * 16);

  // i-row metadata at C/D row positions: row = fi*16 + lg*4 + r
  float sqi[2][4]; int mi[2][4];
  #pragma unroll
  for (int fi = 0; fi < 2; fi++)
    #pragma unroll
    for (int r = 0; r < 4; r++) {
      int ir = i0 + fi * 16 + lg * 4 + r;
      sqi[fi][r] = sq[ir]; mi[fi][r] = maskA[ir];
    }

  bool diag = (bi == bj);
  float sum = 0.0f;

  s16x8 B0[2][4], B1[2][4];
  float sqj0[2], sqj1[2]; int mj0[2], mj1[2];

  auto loadB = [&](s16x8 (&B)[2][4], int j0s) {
    #pragma unroll
    for (int fj = 0; fj < 2; fj++)
      #pragma unroll
      for (int ks = 0; ks < 4; ks++)
        B[fj][ks] = *reinterpret_cast<const s16x8*>(
            fb + (size_t)(j0s + fj * 16 + l15) * 256 + ks * 64 + lg * 16);
  };
  auto loadM = [&](float (&sqj)[2], int (&mj)[2], int j0s) {
    #pragma unroll
    for (int fj = 0; fj < 2; fj++) {
      int jr = j0s + fj * 16 + l15;
      sqj[fj] = sq[jr]; mj[fj] = maskA[jr];
    }
  };
  auto domfma = [&](s16x8 (&B)[2][4], f32x4 (&acc)[2][2]) {
    #pragma unroll
    for (int fi = 0; fi < 2; fi++)
      #pragma unroll
      for (int fj = 0; fj < 2; fj++)
        acc[fi][fj] = (f32x4){0.f, 0.f, 0.f, 0.f};
    #pragma unroll
    for (int ks = 0; ks < 4; ks++)
      #pragma unroll
      for (int fi = 0; fi < 2; fi++)
        #pragma unroll
        for (int fj = 0; fj < 2; fj++)
          acc[fi][fj] = __builtin_amdgcn_mfma_f32_16x16x32_bf16(
              af[fi][ks], B[fj][ks], acc[fi][fj], 0, 0, 0);
  };
  auto epilogue = [&](f32x4 (&acc)[2][2], float (&sqj)[2], int (&mj)[2], int js) {
    #pragma unroll
    for (int fi = 0; fi < 2; fi++)
      #pragma unroll
      for (int fj = 0; fj < 2; fj++)
        #pragma unroll
        for (int r = 0; r < 4; r++) {
          float g  = acc[fi][fj][r];
          float d2 = fmaf(-2.0f, g, sqi[fi][r] + sqj[fj]);
          float t  = fminf(FSQRT(fmaxf(d2, 0.0f)), MARGINP);
          int inter = __popc(mi[fi][r] & mj[fj]);
          int uni   = __popc(mi[fi][r] | mj[fj]);
          float w = (float)inter * FRCP((float)uni);
          w = (inter == 0) ? -1.0f : w;      // cndmask also kills the 0*inf NaN path
          if (diag) {
            int il = wv * 32 + fi * 16 + lg * 4 + r;
            int jl = js * 32 + fj * 16 + l15;
            float f = (jl > il) ? 2.0f : ((jl == il) ? 1.0f : 0.0f);
            w *= f;
          }
          sum = fmaf(w, t, sum);
        }
  };

  // static 1-ahead pipeline over the 4 j-subtiles
  f32x4 accA[2][2], accB[2][2], accC[2][2], accD[2][2];
  loadB(B0, j0);        loadM(sqj0, mj0, j0);
  loadB(B1, j0 + 32);   loadM(sqj1, mj1, j0 + 32);
  domfma(B0, accA);
  loadB(B0, j0 + 64);                 // issue js2 B under js0 epilogue
  epilogue(accA, sqj0, mj0, 0);
  loadM(sqj0, mj0, j0 + 64);
  domfma(B1, accB);
  loadB(B1, j0 + 96);                 // issue js3 B under js1 epilogue
  epilogue(accB, sqj1, mj1, 1);
  loadM(sqj1, mj1, j0 + 96);
  domfma(B0, accC);
  epilogue(accC, sqj0, mj0, 2);
  domfma(B1, accD);
  epilogue(accD, sqj1, mj1, 3);

  #pragma unroll
  for (int off = 32; off >= 1; off >>= 1) sum += __shfl_xor(sum, off);
  if (lane == 0) bsum[wv] = sum;
  __syncthreads();
  if (threadIdx.x == 0) {
    float s = bsum[0] + bsum[1] + bsum[2] + bsum[3];
    part[blockIdx.x] = diag ? s : 2.0f * s;   // one plain store per block, no atomics
  }
}

// Single block: sum 2080 partials (double accum) + apply deferred scales.
__global__ void reduce_kernel(const float* __restrict__ part, float* __restrict__ out) {
  int tid = threadIdx.x;
  double s = 0.0;
  for (int i = tid; i < NTILE; i += 256) s += (double)part[i];
  #pragma unroll
  for (int off = 32; off >= 1; off >>= 1) s += __shfl_xor(s, off);
  __shared__ double wsum[4];
  int wv = tid >> 6, lane = tid & 63;
  if (lane == 0) wsum[wv] = s;
  __syncthreads();
  if (tid == 0) {
    double t = wsum[0] + wsum[1] + wsum[2] + wsum[3];
    // undo deferred scales: /sqrt(128) and /n^2
    out[0] = (float)(t * (1.0 / (11.313708498984760 * 67108864.0)));
  }
}

extern "C" void kernel_launch(void* const* d_in, const int* in_sizes, int n_in,
                              void* d_out, int out_size, void* d_ws, size_t ws_size,
                              hipStream_t stream) {
  const float* feat  = (const float*)d_in[0];
  const int*   label = (const int*)d_in[1];
  char* ws = (char*)d_ws;
  float* part           = (float*)ws;                         // 2080 floats (8448 B reserved)
  float* sq             = (float*)(ws + 8448);                // 32 KB
  int*   maskA          = (int*)(ws + 8448 + 32768);          // 32 KB
  unsigned short* fbf   = (unsigned short*)(ws + 8448 + 65536); // 2 MB bf16 feature
  float* out = (float*)d_out;

  prep_kernel<<<NROW / 4, 256, 0, stream>>>(feat, label, fbf, sq, maskA);
  pair_main<<<NTILE, 256, 0, stream>>>(fbf, sq, maskA, part);
  reduce_kernel<<<1, 256, 0, stream>>>(part, out);
}